// Round 13
// baseline (135.335 us; speedup 1.0000x reference)
//
#include <hip/hip_runtime.h>
#include <math.h>

// MoE router on MFMA: logits = (x @ W1^T + b1) @ W2^T + b2; softmax; top-2; masks.
// N=32768, D=1024, D_H=512, E=8, K=2.
//
// Split-fp16: x = xh+xl, W1 = wh+wl; h = xh*wh + xl*wh + xh*wl (3 MFMA passes,
// fp32 acc). W1 pre-split/pre-packed into 32x32x16 fragment order in d_ws (r4).
//
// Round-13: r12 shell + ONE change: the 24 MFMAs per ktile are reordered from
// same-accumulator TRIPLES (dep distance 1 -- wave stalls ~latency per MFMA,
// in-order issue) to pass-major interleave with dep distance 8 (~260 cyc
// cover). CDNA waves issue in order; with 2 waves/SIMD, dependent-MFMA
// latency was never hidden. HK's 70%-of-peak GEMM at the same occupancy uses
// 16-independent-MFMA clusters -- this is the missing piece. Mid-iteration
// s_barrier removed (only existed to split the clusters).

#define N_TOK 32768
#define D_IN  1024
#define D_H   512
#define N_EXP 8

#define BM      128
#define BK      16
#define THREADS 512
#define NKT     (D_IN / BK)   // 64 k-tiles
#define WSLOTS  (NKT * 1024)  // W1 frag slots per hi/lo plane

typedef _Float16 f16;
typedef __attribute__((ext_vector_type(4)))  _Float16 f16x4;
typedef __attribute__((ext_vector_type(8)))  _Float16 f16x8;
typedef __attribute__((ext_vector_type(16))) float    f32x16;

#define MFMA(a, b, c) __builtin_amdgcn_mfma_f32_32x32x16_f16((a), (b), (c), 0, 0, 0)

// raw k-loop barrier: LDS-order only, NO vmcnt drain (keeps B/x prefetch alive)
#define KBAR() do {                                                            \
        asm volatile("s_waitcnt lgkmcnt(0)" ::: "memory");                     \
        __builtin_amdgcn_s_barrier();                                          \
        __builtin_amdgcn_sched_barrier(0);                                     \
    } while (0)

// ---- pre-kernel: split W1 into hi/lo f16 fragments in ws (verified r4-r12) ----
__global__ void split_w1(const float* __restrict__ W1,
                         f16* __restrict__ wsH, f16* __restrict__ wsL) {
    const int s = blockIdx.x * 256 + threadIdx.x;   // 0..65535
    const int kt  = s >> 10;
    const int ctg = (s >> 6) & 15;
    const int l   = s & 63;
    const int n   = ctg * 32 + (l & 31);
    const int k   = kt * BK + (l >> 5) * 8;
    const float* src = &W1[(size_t)n * D_IN + k];
    float4 a0 = *(const float4*)src;
    float4 a1 = *(const float4*)(src + 4);
    f16x8 hi, lo;
#pragma unroll
    for (int j = 0; j < 4; ++j) {
        float v0 = ((const float*)&a0)[j];
        float v1 = ((const float*)&a1)[j];
        _Float16 h0 = (_Float16)v0, h1 = (_Float16)v1;
        hi[j] = h0;     hi[j + 4] = h1;
        lo[j] = (_Float16)(v0 - (float)h0);
        lo[j + 4] = (_Float16)(v1 - (float)h1);
    }
    *(f16x8*)&wsH[(size_t)s * 8] = hi;
    *(f16x8*)&wsL[(size_t)s * 8] = lo;
}

// ---- main kernel ----
__global__ __launch_bounds__(THREADS, 1)   // 1 block/CU -> 2 waves/SIMD -> 256 unified regs
void moe_router_mfma(const float* __restrict__ x,
                     const f16* __restrict__ wH,
                     const f16* __restrict__ wL,
                     const float* __restrict__ b1,
                     const float* __restrict__ W2,
                     const float* __restrict__ b2,
                     float* __restrict__ out)
{
    __shared__ __align__(16) f16   AS[2 * 2 * 2048];     // A frags dbuf: 16 KB
    __shared__ __align__(16) float h_s[32 * 512];        // epilogue h: 64 KB
    __shared__ __align__(16) float W2s[N_EXP * D_H];     // 16 KB
    __shared__ __align__(16) float b1s[D_H];             // 2 KB
    __shared__ float b2s[N_EXP];

    const int t    = threadIdx.x;
    const int w    = t >> 6;
    const int lane = t & 63;
    const int m0   = blockIdx.x * BM;

    // 8 accumulators: row-tile rt=0..3 x col c=0..1 (wave owns cols 2w,2w+1)
    f32x16 a0c0 = {}, a0c1 = {}, a1c0 = {}, a1c1 = {};
    f32x16 a2c0 = {}, a2c1 = {}, a3c0 = {}, a3c1 = {};

    // A staging geometry (verified r4-r12): thread t -> frag fA=t>>1, qA=t&1.
    const int fA   = t >> 1;
    const int qA   = t & 1;
    const int rowA = (fA >> 6) * 32 + (fA & 31);
    const int kA   = ((fA >> 5) & 1) * 8 + qA * 4;
    const float* xsrc = x + (size_t)(m0 + rowA) * D_IN + kA;
    const int aDst = fA * 8 + qA * 4;

    // B frag offsets for this wave (f16 elems within one ktile plane)
    const size_t bOff0 = (size_t)(2 * w + 0) * 512 + (size_t)lane * 8;
    const size_t bOff1 = (size_t)(2 * w + 1) * 512 + (size_t)lane * 8;

    auto stageAwrite = [&](const float4& xv, int buf) {
        f16x4 hi, lo;
        float v[4] = {xv.x, xv.y, xv.z, xv.w};
#pragma unroll
        for (int j = 0; j < 4; ++j) {
            _Float16 h = (_Float16)v[j];
            hi[j] = h;
            lo[j] = (_Float16)(v[j] - (float)h);
        }
        *(f16x4*)&AS[(buf * 2 + 0) * 2048 + aDst] = hi;
        *(f16x4*)&AS[(buf * 2 + 1) * 2048 + aDst] = lo;
    };

    // ---- prologue: B regs + A LDS for ktile 0 ----
    f16x8 Bh0A = *(const f16x8*)(wH + bOff0);
    f16x8 Bh1A = *(const f16x8*)(wH + bOff1);
    f16x8 Bl0A = *(const f16x8*)(wL + bOff0);
    f16x8 Bl1A = *(const f16x8*)(wL + bOff1);
    f16x8 Bh0B, Bh1B, Bl0B, Bl1B;
    {
        float4 xv = *(const float4*)xsrc;
        stageAwrite(xv, 0);
    }
    __syncthreads();

    // One ktile body. BUF = A-buffer of this ktile; B cur regs named in;
    // B next regs named out (loaded here, consumed next body).
    // MFMA cluster: pass-major, same-acc dep distance 8.
#define BODY(BUF, KT, BH0, BH1, BL0, BL1, NH0, NH1, NL0, NL1) do {             \
        float4 xnxt = {0.f, 0.f, 0.f, 0.f};                                    \
        if ((KT) + 1 < NKT) {                                                  \
            const size_t nb = (size_t)((KT) + 1) * 8192;                       \
            NH0 = *(const f16x8*)(wH + nb + bOff0);                            \
            NH1 = *(const f16x8*)(wH + nb + bOff1);                            \
            NL0 = *(const f16x8*)(wL + nb + bOff0);                            \
            NL1 = *(const f16x8*)(wL + nb + bOff1);                            \
            xnxt = *(const float4*)(xsrc + (size_t)((KT) + 1) * BK);           \
        }                                                                      \
        const f16* ah = &AS[((BUF) * 2 + 0) * 2048];                           \
        const f16* al = &AS[((BUF) * 2 + 1) * 2048];                           \
        f16x8 ah0 = *(const f16x8*)&ah[(0 * 64 + lane) * 8];                   \
        f16x8 al0 = *(const f16x8*)&al[(0 * 64 + lane) * 8];                   \
        f16x8 ah1 = *(const f16x8*)&ah[(1 * 64 + lane) * 8];                   \
        f16x8 al1 = *(const f16x8*)&al[(1 * 64 + lane) * 8];                   \
        f16x8 ah2 = *(const f16x8*)&ah[(2 * 64 + lane) * 8];                   \
        f16x8 al2 = *(const f16x8*)&al[(2 * 64 + lane) * 8];                   \
        f16x8 ah3 = *(const f16x8*)&ah[(3 * 64 + lane) * 8];                   \
        f16x8 al3 = *(const f16x8*)&al[(3 * 64 + lane) * 8];                   \
        __builtin_amdgcn_s_setprio(1);                                         \
        /* pass 1: xh * wh  (8 independent) */                                 \
        a0c0 = MFMA(ah0, BH0, a0c0);                                           \
        a1c0 = MFMA(ah1, BH0, a1c0);                                           \
        a2c0 = MFMA(ah2, BH0, a2c0);                                           \
        a3c0 = MFMA(ah3, BH0, a3c0);                                           \
        a0c1 = MFMA(ah0, BH1, a0c1);                                           \
        a1c1 = MFMA(ah1, BH1, a1c1);                                           \
        a2c1 = MFMA(ah2, BH1, a2c1);                                           \
        a3c1 = MFMA(ah3, BH1, a3c1);                                           \
        /* pass 2: xl * wh  (dep distance 8 from pass 1) */                    \
        a0c0 = MFMA(al0, BH0, a0c0);                                           \
        a1c0 = MFMA(al1, BH0, a1c0);                                           \
        a2c0 = MFMA(al2, BH0, a2c0);                                           \
        a3c0 = MFMA(al3, BH0, a3c0);                                           \
        a0c1 = MFMA(al0, BH1, a0c1);                                           \
        a1c1 = MFMA(al1, BH1, a1c1);                                           \
        a2c1 = MFMA(al2, BH1, a2c1);                                           \
        a3c1 = MFMA(al3, BH1, a3c1);                                           \
        /* pass 3: xh * wl  (dep distance 8 from pass 2) */                    \
        a0c0 = MFMA(ah0, BL0, a0c0);                                           \
        a1c0 = MFMA(ah1, BL0, a1c0);                                           \
        a2c0 = MFMA(ah2, BL0, a2c0);                                           \
        a3c0 = MFMA(ah3, BL0, a3c0);                                           \
        a0c1 = MFMA(ah0, BL1, a0c1);                                           \
        a1c1 = MFMA(ah1, BL1, a1c1);                                           \
        a2c1 = MFMA(ah2, BL1, a2c1);                                           \
        a3c1 = MFMA(ah3, BL1, a3c1);                                           \
        __builtin_amdgcn_s_setprio(0);                                         \
        if ((KT) + 1 < NKT) stageAwrite(xnxt, (BUF) ^ 1);                      \
        KBAR();   /* lgkm-only barrier: B/x prefetch stays in flight */        \
    } while (0)

    for (int kt = 0; kt < NKT; kt += 2) {
        BODY(0, kt,     Bh0A, Bh1A, Bl0A, Bl1A, Bh0B, Bh1B, Bl0B, Bl1B);
        BODY(1, kt + 1, Bh0B, Bh1B, Bl0B, Bl1B, Bh0A, Bh1A, Bl0A, Bl1A);
    }
#undef BODY

    // ---- epilogue (router tail verified r4-r12) ----
    ((float4*)W2s)[t * 2]     = ((const float4*)W2)[t * 2];
    ((float4*)W2s)[t * 2 + 1] = ((const float4*)W2)[t * 2 + 1];
    if (t < D_H / 4) ((float4*)b1s)[t] = ((const float4*)b1)[t];
    if (t < N_EXP) b2s[t] = b2[t];
    __syncthreads();

    const int n0  = w * 64 + (lane & 31);   // C/D layout: col = lane&31
    const int n1  = n0 + 32;
    const float bn0 = b1s[n0];
    const float bn1 = b1s[n1];

    float* out_logits = out;
    float* out_w      = out + (size_t)N_TOK * N_EXP;
    float* out_i      = out_w + (size_t)N_TOK * 2;
    float* out_m      = out_i + (size_t)N_TOK * 2;

    auto reduce_rows = [&](int rt) {
#pragma unroll
        for (int rr2 = 0; rr2 < 4; ++rr2) {
            const int rl   = w * 4 + rr2;            // 8 waves x 4 = 32 rows
            const int grow = m0 + rt * 32 + rl;
            float4 ha = *(const float4*)&h_s[rl * 512 + lane * 4];
            float4 hb = *(const float4*)&h_s[rl * 512 + 256 + lane * 4];
            float v1 = -3.4e38f, v2 = -3.4e38f;
            int   i1 = 0, i2 = 0;
            float pls[8];
#pragma unroll
            for (int e = 0; e < N_EXP; ++e) {
                float4 wa = *(const float4*)&W2s[e * D_H + lane * 4];
                float4 wb = *(const float4*)&W2s[e * D_H + 256 + lane * 4];
                float s = ha.x * wa.x;
                s = fmaf(ha.y, wa.y, s);
                s = fmaf(ha.z, wa.z, s);
                s = fmaf(ha.w, wa.w, s);
                s = fmaf(hb.x, wb.x, s);
                s = fmaf(hb.y, wb.y, s);
                s = fmaf(hb.z, wb.z, s);
                s = fmaf(hb.w, wb.w, s);
#pragma unroll
                for (int off = 1; off < 64; off <<= 1)
                    s += __shfl_xor(s, off);
                s += b2s[e];
                pls[e] = s;
                if (s > v1)      { v2 = v1; i2 = i1; v1 = s; i1 = e; }
                else if (s > v2) { v2 = s;  i2 = e; }
            }
            const float rr   = expf(v2 - v1);
            const float wden = 1.f / (1.f + rr);
            if (lane == 0) {
                float4 lo4 = {pls[0], pls[1], pls[2], pls[3]};
                float4 hi4 = {pls[4], pls[5], pls[6], pls[7]};
                *(float4*)&out_logits[(size_t)grow * N_EXP]     = lo4;
                *(float4*)&out_logits[(size_t)grow * N_EXP + 4] = hi4;
                float2 wv = {wden, rr * wden};
                *(float2*)&out_w[(size_t)grow * 2] = wv;
                float2 iv = {(float)i1, (float)i2};
                *(float2*)&out_i[(size_t)grow * 2] = iv;
            }
            if (lane < 16) {
                const int e   = lane >> 1;
                const int kk  = lane & 1;
                const int sel = kk ? i2 : i1;
                out_m[((size_t)(e * 2 + kk)) * N_TOK + grow] = (sel == e) ? 1.0f : 0.0f;
            }
        }
    };

    // C/D row map (verified): in-tile row = (rr&3) + 8*(rr>>2) + 4*(lane>>5)
#define DO_GROUP(AC0, AC1, RT) do {                                            \
        _Pragma("unroll")                                                      \
        for (int rr = 0; rr < 16; ++rr) {                                      \
            const int rl = (rr & 3) + 8 * (rr >> 2) + 4 * (lane >> 5);         \
            h_s[rl * 512 + n0] = AC0[rr] + bn0;                                \
            h_s[rl * 512 + n1] = AC1[rr] + bn1;                                \
        }                                                                      \
        __syncthreads();                                                       \
        reduce_rows(RT);                                                       \
        __syncthreads();                                                       \
    } while (0)

    DO_GROUP(a0c0, a0c1, 0);
    DO_GROUP(a1c0, a1c1, 1);
    DO_GROUP(a2c0, a2c1, 2);
    DO_GROUP(a3c0, a3c1, 3);
#undef DO_GROUP
}

extern "C" void kernel_launch(void* const* d_in, const int* in_sizes, int n_in,
                              void* d_out, int out_size, void* d_ws, size_t ws_size,
                              hipStream_t stream) {
    const float* x  = (const float*)d_in[0];
    const float* W1 = (const float*)d_in[1];
    const float* b1 = (const float*)d_in[2];
    const float* W2 = (const float*)d_in[3];
    const float* b2 = (const float*)d_in[4];
    float* out = (float*)d_out;

    f16* wsH = (f16*)d_ws;                       // 1 MB
    f16* wsL = wsH + (size_t)WSLOTS * 8;         // 1 MB

    split_w1<<<WSLOTS / 256, 256, 0, stream>>>(W1, wsH, wsL);
    moe_router_mfma<<<N_TOK / BM, THREADS, 0, stream>>>(x, wsH, wsL, b1, W2, b2, out);
}

// Round 14
// 131.308 us; speedup vs baseline: 1.0307x; 1.0307x over previous
//
#include <hip/hip_runtime.h>
#include <math.h>

// MoE router on MFMA: logits = (x @ W1^T + b1) @ W2^T + b2; softmax; top-2; masks.
// N=32768, D=1024, D_H=512, E=8, K=2.
//
// Split-fp16: x = xh+xl, W1 = wh+wl; h = xh*wh + xl*wh + xh*wl (3 MFMA passes,
// fp32 acc). W1 pre-split/pre-packed into 32x32x16 fragment order in d_ws (r4).
//
// Round-14: r13 + full cross-iteration x REGISTER PIPELINE. r12/r13 still had
// one same-iteration VMEM wait: stageAwrite cvt'd an x value loaded at the top
// of the SAME iteration (vmcnt wait ~500-900cyc, queued behind 4 B loads,
// sitting right before the barrier -> inflates every wave's barrier arrival).
// Now iter k consumes x(k+1) loaded at iter k-1 (full-iteration cover, zero
// stall) and issues x(k+2). stageAwrite moved to iter TOP so LDS writes finish
// early and KBAR's lgkmcnt(0) is ~free.

#define N_TOK 32768
#define D_IN  1024
#define D_H   512
#define N_EXP 8

#define BM      128
#define BK      16
#define THREADS 512
#define NKT     (D_IN / BK)   // 64 k-tiles
#define WSLOTS  (NKT * 1024)  // W1 frag slots per hi/lo plane

typedef _Float16 f16;
typedef __attribute__((ext_vector_type(4)))  _Float16 f16x4;
typedef __attribute__((ext_vector_type(8)))  _Float16 f16x8;
typedef __attribute__((ext_vector_type(16))) float    f32x16;

#define MFMA(a, b, c) __builtin_amdgcn_mfma_f32_32x32x16_f16((a), (b), (c), 0, 0, 0)

// raw k-loop barrier: LDS-order only, NO vmcnt drain (keeps B/x prefetch alive)
#define KBAR() do {                                                            \
        asm volatile("s_waitcnt lgkmcnt(0)" ::: "memory");                     \
        __builtin_amdgcn_s_barrier();                                          \
        __builtin_amdgcn_sched_barrier(0);                                     \
    } while (0)

// ---- pre-kernel: split W1 into hi/lo f16 fragments in ws (verified r4-r13) ----
__global__ void split_w1(const float* __restrict__ W1,
                         f16* __restrict__ wsH, f16* __restrict__ wsL) {
    const int s = blockIdx.x * 256 + threadIdx.x;   // 0..65535
    const int kt  = s >> 10;
    const int ctg = (s >> 6) & 15;
    const int l   = s & 63;
    const int n   = ctg * 32 + (l & 31);
    const int k   = kt * BK + (l >> 5) * 8;
    const float* src = &W1[(size_t)n * D_IN + k];
    float4 a0 = *(const float4*)src;
    float4 a1 = *(const float4*)(src + 4);
    f16x8 hi, lo;
#pragma unroll
    for (int j = 0; j < 4; ++j) {
        float v0 = ((const float*)&a0)[j];
        float v1 = ((const float*)&a1)[j];
        _Float16 h0 = (_Float16)v0, h1 = (_Float16)v1;
        hi[j] = h0;     hi[j + 4] = h1;
        lo[j] = (_Float16)(v0 - (float)h0);
        lo[j + 4] = (_Float16)(v1 - (float)h1);
    }
    *(f16x8*)&wsH[(size_t)s * 8] = hi;
    *(f16x8*)&wsL[(size_t)s * 8] = lo;
}

// ---- main kernel ----
__global__ __launch_bounds__(THREADS, 1)   // 1 block/CU -> 2 waves/SIMD -> 256 unified regs
void moe_router_mfma(const float* __restrict__ x,
                     const f16* __restrict__ wH,
                     const f16* __restrict__ wL,
                     const float* __restrict__ b1,
                     const float* __restrict__ W2,
                     const float* __restrict__ b2,
                     float* __restrict__ out)
{
    __shared__ __align__(16) f16   AS[2 * 2 * 2048];     // A frags dbuf: 16 KB
    __shared__ __align__(16) float h_s[32 * 512];        // epilogue h: 64 KB
    __shared__ __align__(16) float W2s[N_EXP * D_H];     // 16 KB
    __shared__ __align__(16) float b1s[D_H];             // 2 KB
    __shared__ float b2s[N_EXP];

    const int t    = threadIdx.x;
    const int w    = t >> 6;
    const int lane = t & 63;
    const int m0   = blockIdx.x * BM;

    // 8 accumulators: row-tile rt=0..3 x col c=0..1 (wave owns cols 2w,2w+1)
    f32x16 a0c0 = {}, a0c1 = {}, a1c0 = {}, a1c1 = {};
    f32x16 a2c0 = {}, a2c1 = {}, a3c0 = {}, a3c1 = {};

    // A staging geometry (verified r4-r13): thread t -> frag fA=t>>1, qA=t&1.
    const int fA   = t >> 1;
    const int qA   = t & 1;
    const int rowA = (fA >> 6) * 32 + (fA & 31);
    const int kA   = ((fA >> 5) & 1) * 8 + qA * 4;
    const float* xsrc = x + (size_t)(m0 + rowA) * D_IN + kA;
    const int aDst = fA * 8 + qA * 4;

    // B frag offsets for this wave (f16 elems within one ktile plane)
    const size_t bOff0 = (size_t)(2 * w + 0) * 512 + (size_t)lane * 8;
    const size_t bOff1 = (size_t)(2 * w + 1) * 512 + (size_t)lane * 8;

    auto stageAwrite = [&](const float4& xv, int buf) {
        f16x4 hi, lo;
        float v[4] = {xv.x, xv.y, xv.z, xv.w};
#pragma unroll
        for (int j = 0; j < 4; ++j) {
            _Float16 h = (_Float16)v[j];
            hi[j] = h;
            lo[j] = (_Float16)(v[j] - (float)h);
        }
        *(f16x4*)&AS[(buf * 2 + 0) * 2048 + aDst] = hi;
        *(f16x4*)&AS[(buf * 2 + 1) * 2048 + aDst] = lo;
    };

    // ---- prologue ----
    // A(0) staged directly; x(1) issued into the held register (consumed at
    // iter 0 top to write A(1)); B(0) pack loaded.
    f16x8 Bh0A = *(const f16x8*)(wH + bOff0);
    f16x8 Bh1A = *(const f16x8*)(wH + bOff1);
    f16x8 Bl0A = *(const f16x8*)(wL + bOff0);
    f16x8 Bl1A = *(const f16x8*)(wL + bOff1);
    f16x8 Bh0B, Bh1B, Bl0B, Bl1B;
    stageAwrite(*(const float4*)xsrc, 0);
    float4 xrA = *(const float4*)(xsrc + (size_t)1 * BK);   // x(1)
    float4 xrB;
    __syncthreads();

    // One ktile body. BUF = A-buffer of this ktile; B cur regs named in;
    // B next named out. XHELD = x(KT+1), arrived (issued last iter);
    // XNEXT <- issue x(KT+2).
#define BODY(BUF, KT, BH0, BH1, BL0, BL1, NH0, NH1, NL0, NL1, XHELD, XNEXT)    \
    do {                                                                       \
        if ((KT) + 2 < NKT)                                                    \
            XNEXT = *(const float4*)(xsrc + (size_t)((KT) + 2) * BK);          \
        if ((KT) + 1 < NKT)                                                    \
            stageAwrite(XHELD, (BUF) ^ 1);   /* zero-stall: full-iter cover */ \
        if ((KT) + 1 < NKT) {                                                  \
            const size_t nb = (size_t)((KT) + 1) * 8192;                       \
            NH0 = *(const f16x8*)(wH + nb + bOff0);                            \
            NH1 = *(const f16x8*)(wH + nb + bOff1);                            \
            NL0 = *(const f16x8*)(wL + nb + bOff0);                            \
            NL1 = *(const f16x8*)(wL + nb + bOff1);                            \
        }                                                                      \
        const f16* ah = &AS[((BUF) * 2 + 0) * 2048];                           \
        const f16* al = &AS[((BUF) * 2 + 1) * 2048];                           \
        f16x8 ah0 = *(const f16x8*)&ah[(0 * 64 + lane) * 8];                   \
        f16x8 al0 = *(const f16x8*)&al[(0 * 64 + lane) * 8];                   \
        f16x8 ah1 = *(const f16x8*)&ah[(1 * 64 + lane) * 8];                   \
        f16x8 al1 = *(const f16x8*)&al[(1 * 64 + lane) * 8];                   \
        f16x8 ah2 = *(const f16x8*)&ah[(2 * 64 + lane) * 8];                   \
        f16x8 al2 = *(const f16x8*)&al[(2 * 64 + lane) * 8];                   \
        f16x8 ah3 = *(const f16x8*)&ah[(3 * 64 + lane) * 8];                   \
        f16x8 al3 = *(const f16x8*)&al[(3 * 64 + lane) * 8];                   \
        __builtin_amdgcn_s_setprio(1);                                         \
        /* pass 1: xh * wh  (8 independent) */                                 \
        a0c0 = MFMA(ah0, BH0, a0c0);                                           \
        a1c0 = MFMA(ah1, BH0, a1c0);                                           \
        a2c0 = MFMA(ah2, BH0, a2c0);                                           \
        a3c0 = MFMA(ah3, BH0, a3c0);                                           \
        a0c1 = MFMA(ah0, BH1, a0c1);                                           \
        a1c1 = MFMA(ah1, BH1, a1c1);                                           \
        a2c1 = MFMA(ah2, BH1, a2c1);                                           \
        a3c1 = MFMA(ah3, BH1, a3c1);                                           \
        /* pass 2: xl * wh  (dep distance 8) */                                \
        a0c0 = MFMA(al0, BH0, a0c0);                                           \
        a1c0 = MFMA(al1, BH0, a1c0);                                           \
        a2c0 = MFMA(al2, BH0, a2c0);                                           \
        a3c0 = MFMA(al3, BH0, a3c0);                                           \
        a0c1 = MFMA(al0, BH1, a0c1);                                           \
        a1c1 = MFMA(al1, BH1, a1c1);                                           \
        a2c1 = MFMA(al2, BH1, a2c1);                                           \
        a3c1 = MFMA(al3, BH1, a3c1);                                           \
        /* pass 3: xh * wl  (dep distance 8) */                                \
        a0c0 = MFMA(ah0, BL0, a0c0);                                           \
        a1c0 = MFMA(ah1, BL0, a1c0);                                           \
        a2c0 = MFMA(ah2, BL0, a2c0);                                           \
        a3c0 = MFMA(ah3, BL0, a3c0);                                           \
        a0c1 = MFMA(ah0, BL1, a0c1);                                           \
        a1c1 = MFMA(ah1, BL1, a1c1);                                           \
        a2c1 = MFMA(ah2, BL1, a2c1);                                           \
        a3c1 = MFMA(ah3, BL1, a3c1);                                           \
        __builtin_amdgcn_s_setprio(0);                                         \
        KBAR();   /* lgkm-only barrier: B/x prefetch stays in flight */        \
    } while (0)

    for (int kt = 0; kt < NKT; kt += 2) {
        BODY(0, kt,     Bh0A, Bh1A, Bl0A, Bl1A, Bh0B, Bh1B, Bl0B, Bl1B, xrA, xrB);
        BODY(1, kt + 1, Bh0B, Bh1B, Bl0B, Bl1B, Bh0A, Bh1A, Bl0A, Bl1A, xrB, xrA);
    }
#undef BODY

    // ---- epilogue (router tail verified r4-r13) ----
    ((float4*)W2s)[t * 2]     = ((const float4*)W2)[t * 2];
    ((float4*)W2s)[t * 2 + 1] = ((const float4*)W2)[t * 2 + 1];
    if (t < D_H / 4) ((float4*)b1s)[t] = ((const float4*)b1)[t];
    if (t < N_EXP) b2s[t] = b2[t];
    __syncthreads();

    const int n0  = w * 64 + (lane & 31);   // C/D layout: col = lane&31
    const int n1  = n0 + 32;
    const float bn0 = b1s[n0];
    const float bn1 = b1s[n1];

    float* out_logits = out;
    float* out_w      = out + (size_t)N_TOK * N_EXP;
    float* out_i      = out_w + (size_t)N_TOK * 2;
    float* out_m      = out_i + (size_t)N_TOK * 2;

    auto reduce_rows = [&](int rt) {
#pragma unroll
        for (int rr2 = 0; rr2 < 4; ++rr2) {
            const int rl   = w * 4 + rr2;            // 8 waves x 4 = 32 rows
            const int grow = m0 + rt * 32 + rl;
            float4 ha = *(const float4*)&h_s[rl * 512 + lane * 4];
            float4 hb = *(const float4*)&h_s[rl * 512 + 256 + lane * 4];
            float v1 = -3.4e38f, v2 = -3.4e38f;
            int   i1 = 0, i2 = 0;
            float pls[8];
#pragma unroll
            for (int e = 0; e < N_EXP; ++e) {
                float4 wa = *(const float4*)&W2s[e * D_H + lane * 4];
                float4 wb = *(const float4*)&W2s[e * D_H + 256 + lane * 4];
                float s = ha.x * wa.x;
                s = fmaf(ha.y, wa.y, s);
                s = fmaf(ha.z, wa.z, s);
                s = fmaf(ha.w, wa.w, s);
                s = fmaf(hb.x, wb.x, s);
                s = fmaf(hb.y, wb.y, s);
                s = fmaf(hb.z, wb.z, s);
                s = fmaf(hb.w, wb.w, s);
#pragma unroll
                for (int off = 1; off < 64; off <<= 1)
                    s += __shfl_xor(s, off);
                s += b2s[e];
                pls[e] = s;
                if (s > v1)      { v2 = v1; i2 = i1; v1 = s; i1 = e; }
                else if (s > v2) { v2 = s;  i2 = e; }
            }
            const float rr   = expf(v2 - v1);
            const float wden = 1.f / (1.f + rr);
            if (lane == 0) {
                float4 lo4 = {pls[0], pls[1], pls[2], pls[3]};
                float4 hi4 = {pls[4], pls[5], pls[6], pls[7]};
                *(float4*)&out_logits[(size_t)grow * N_EXP]     = lo4;
                *(float4*)&out_logits[(size_t)grow * N_EXP + 4] = hi4;
                float2 wv = {wden, rr * wden};
                *(float2*)&out_w[(size_t)grow * 2] = wv;
                float2 iv = {(float)i1, (float)i2};
                *(float2*)&out_i[(size_t)grow * 2] = iv;
            }
            if (lane < 16) {
                const int e   = lane >> 1;
                const int kk  = lane & 1;
                const int sel = kk ? i2 : i1;
                out_m[((size_t)(e * 2 + kk)) * N_TOK + grow] = (sel == e) ? 1.0f : 0.0f;
            }
        }
    };

    // C/D row map (verified): in-tile row = (rr&3) + 8*(rr>>2) + 4*(lane>>5)
#define DO_GROUP(AC0, AC1, RT) do {                                            \
        _Pragma("unroll")                                                      \
        for (int rr = 0; rr < 16; ++rr) {                                      \
            const int rl = (rr & 3) + 8 * (rr >> 2) + 4 * (lane >> 5);         \
            h_s[rl * 512 + n0] = AC0[rr] + bn0;                                \
            h_s[rl * 512 + n1] = AC1[rr] + bn1;                                \
        }                                                                      \
        __syncthreads();                                                       \
        reduce_rows(RT);                                                       \
        __syncthreads();                                                       \
    } while (0)

    DO_GROUP(a0c0, a0c1, 0);
    DO_GROUP(a1c0, a1c1, 1);
    DO_GROUP(a2c0, a2c1, 2);
    DO_GROUP(a3c0, a3c1, 3);
#undef DO_GROUP
}

extern "C" void kernel_launch(void* const* d_in, const int* in_sizes, int n_in,
                              void* d_out, int out_size, void* d_ws, size_t ws_size,
                              hipStream_t stream) {
    const float* x  = (const float*)d_in[0];
    const float* W1 = (const float*)d_in[1];
    const float* b1 = (const float*)d_in[2];
    const float* W2 = (const float*)d_in[3];
    const float* b2 = (const float*)d_in[4];
    float* out = (float*)d_out;

    f16* wsH = (f16*)d_ws;                       // 1 MB
    f16* wsL = wsH + (size_t)WSLOTS * 8;         // 1 MB

    split_w1<<<WSLOTS / 256, 256, 0, stream>>>(W1, wsH, wsL);
    moe_router_mfma<<<N_TOK / BM, THREADS, 0, stream>>>(x, wsH, wsL, b1, W2, b2, out);
}